// Round 13
// baseline (237.520 us; speedup 1.0000x reference)
//
#include <hip/hip_runtime.h>
#include <hip/hip_bf16.h>

typedef __attribute__((ext_vector_type(8))) short shortx8;
typedef __attribute__((ext_vector_type(4))) float floatx4;
typedef __attribute__((ext_vector_type(16))) float floatx16;
typedef __attribute__((ext_vector_type(4))) unsigned uintx4;
typedef __attribute__((ext_vector_type(2))) unsigned uintx2;

#define B_ 2
#define T_ 2048
#define D_ 1024
#define H_ 16
#define HD_ 64
#define SCALE 0.125f
// log2(e)-folded constants: Q is pre-scaled by SCALE*log2e, softmax uses exp2.
#define QSCALE 0.18033688011112042f   /* 0.125 * log2(e) */
#define SMAX2 23.083120654223414f     /* 16 * log2(e) */
#define FULLH ((size_t)B_ * H_ * T_ * HD_)

// async global->LDS, 16B per lane; LDS dest = wave-uniform base + lane*16
#define GLDS16(g, l) __builtin_amdgcn_global_load_lds( \
    (__attribute__((address_space(1))) void*)(g), \
    (__attribute__((address_space(3))) void*)(l), 16, 0, 0)

__device__ __forceinline__ short f2bf(float f) {
    union { float f; unsigned u; } v; v.f = f;
    unsigned r = v.u + 0x7FFFu + ((v.u >> 16) & 1u);
    return (short)(r >> 16);
}

__device__ __forceinline__ unsigned pk2(float x, float y) {
    union { __hip_bfloat162 h; unsigned u; } t;
    t.h = __float22bfloat162_rn(make_float2(x, y));
    return t.u;
}

__device__ __forceinline__ shortx8 cvt8(floatx4 a, floatx4 b) {
    uintx4 r = { pk2(a[0], a[1]), pk2(a[2], a[3]), pk2(b[0], b[1]), pk2(b[2], b[3]) };
    return __builtin_bit_cast(shortx8, r);
}

__device__ __forceinline__ float ex2(float x) {
#if __has_builtin(__builtin_amdgcn_exp2f)
    return __builtin_amdgcn_exp2f(x);
#else
    return exp2f(x);
#endif
}

// ================= FAST PATH =================
// Q/K/V projection with FUSED fp32->bf16 conversion (qkv_slow pattern at
// 128x128 tile): reg-staged fp32 loads (prefetch-covered) -> cvt8 ->
// ds_write into padded [128][72] LDS; 2 barriers/K-step. No cvt_xw kernel,
// no xbf/wbf round-trip. Chunked XCD mapping (R12, FETCH-proven): xcd=id&7
// owns bx in {3*xcd..}, iterate {chunk of 8 by} x {3 bx}.
__global__ __launch_bounds__(256) void qkv_fast(const float* __restrict__ x,
                                                const float* __restrict__ wqkv,
                                                short* __restrict__ qout,
                                                short* __restrict__ kv) {
    __shared__ __align__(16) short As[128][72];   // 18 KB
    __shared__ __align__(16) short Bs[128][72];   // 18 KB

    const int tid = threadIdx.x;
    const int wv = tid >> 6;
    const int l  = tid & 63;
    const int ln = l & 15;
    const int quad = l >> 4;
    const int qd   = quad << 3;
    const int rowb = quad << 2;
    const int wm = wv >> 1, wn = wv & 1;

    const int id  = blockIdx.x;
    const int xcd = id & 7;
    const int tt  = id >> 3;               // 0..95
    const int byi = tt & 7;
    const int u   = tt >> 3;               // 0..11
    const int bxl = u % 3;
    const int chunk = u / 3;               // 0..3
    const int bx = xcd * 3 + bxl;          // 0..23
    const int by = chunk * 8 + byi;        // 0..31
    const int m0 = by * 128;
    const int n0g = bx * 128;

    // staging: thread -> row sr, 32 contiguous floats at col sc
    const int sr = tid >> 1;
    const int sc = (tid & 1) << 5;
    const float* agp = x    + (size_t)(m0 + sr) * D_ + sc;
    const float* bgp = wqkv + (size_t)(n0g + sr) * D_ + sc;

    floatx4 fa[8], fb[8];
    auto FETCH = [&](int k0) {
#pragma unroll
        for (int s = 0; s < 8; ++s) {
            fa[s] = *reinterpret_cast<const floatx4*>(agp + k0 + s * 4);
            fb[s] = *reinterpret_cast<const floatx4*>(bgp + k0 + s * 4);
        }
    };
    auto STAGE = [&]() {
#pragma unroll
        for (int s = 0; s < 4; ++s) {
            *reinterpret_cast<shortx8*>(&As[sr][sc + 8 * s]) = cvt8(fa[2 * s], fa[2 * s + 1]);
            *reinterpret_cast<shortx8*>(&Bs[sr][sc + 8 * s]) = cvt8(fb[2 * s], fb[2 * s + 1]);
        }
    };

    floatx4 acc[4][4] = {};

    FETCH(0);
    for (int k0 = 0; k0 < D_; k0 += 64) {
        __syncthreads();
        STAGE();
        __syncthreads();
        if (k0 + 64 < D_) FETCH(k0 + 64);   // issued before COMP -> covered

#pragma unroll
        for (int kk = 0; kk < 2; ++kk) {
            shortx8 af[4], bf[4];
#pragma unroll
            for (int i = 0; i < 4; ++i)
                af[i] = *reinterpret_cast<const shortx8*>(&As[wm * 64 + i * 16 + ln][kk * 32 + qd]);
#pragma unroll
            for (int j = 0; j < 4; ++j)
                bf[j] = *reinterpret_cast<const shortx8*>(&Bs[wn * 64 + j * 16 + ln][kk * 32 + qd]);
#pragma unroll
            for (int i = 0; i < 4; ++i)
#pragma unroll
                for (int j = 0; j < 4; ++j)
                    acc[i][j] = __builtin_amdgcn_mfma_f32_16x16x32_bf16(af[i], bf[j], acc[i][j], 0, 0, 0);
        }
    }

    const int sel = n0g >> 10;
    const int bb = m0 >> 11;
    const int t0w = (m0 + wm * 64) & (T_ - 1);
    const int h = ((n0g + wn * 64) >> 6) & 15;

    if (sel < 2) {
        short* dst = (sel == 0) ? qout : kv;
        const float sc2 = (sel == 0) ? QSCALE : 1.0f;   // Q carries log2e
        const size_t hb = (size_t)(bb * H_ + h) * T_;
#pragma unroll
        for (int i = 0; i < 4; ++i)
#pragma unroll
            for (int r = 0; r < 4; ++r) {
                int t = t0w + i * 16 + rowb + r;
#pragma unroll
                for (int j = 0; j < 4; ++j)
                    dst[(hb + t) * HD_ + j * 16 + ln] = f2bf(acc[i][j][r] * sc2);
            }
    } else {
        // V -> dim-major [b][h][d][t], 2-pass per-wave LDS transpose (As dead)
        __syncthreads();
        short* tb = &As[0][0] + wv * 2304;             // 32 rows x 72 per wave
        short* vhead = kv + FULLH + (size_t)(bb * H_ + h) * HD_ * T_;
        const int dl = l & 31, th = (l >> 5) << 5;
#pragma unroll
        for (int p = 0; p < 2; ++p) {
#pragma unroll
            for (int i = 0; i < 4; ++i)
#pragma unroll
                for (int jj = 0; jj < 2; ++jj) {
                    int j = 2 * p + jj;
#pragma unroll
                    for (int r = 0; r < 4; ++r)
                        tb[(jj * 16 + ln) * 72 + i * 16 + rowb + r] = f2bf(acc[i][j][r]);
                }
            short* vd = vhead + (size_t)(p * 32 + dl) * T_ + t0w + th;
#pragma unroll
            for (int seg = 0; seg < 4; ++seg)
                *reinterpret_cast<shortx8*>(vd + seg * 8) =
                    *reinterpret_cast<const shortx8*>(&tb[dl * 72 + th + seg * 8]);
        }
    }
}

// Final projection, BM=64 x BN=128 (R11 proven version). 1D grid 512:
// bx = id&7 (one B-panel per XCD), by = id>>3 -> 2 blocks/CU.
__global__ __launch_bounds__(256) void out_fast(const short* __restrict__ Abf,
                                                const short* __restrict__ wbf,
                                                float* __restrict__ out) {
    __shared__ __align__(16) short As[64 * 64];    // 8 KB
    __shared__ __align__(16) short Bs[128 * 64];   // 16 KB

    const int tid = threadIdx.x;
    const int wv = tid >> 6;
    const int l  = tid & 63;
    const int ln = l & 15;
    const int quad = l >> 4;
    const int rowb = quad << 2;
    const int wm = wv >> 1, wn = wv & 1;

    const int id = blockIdx.x;
    const int m0 = (id >> 3) * 64;
    const int n0g = (id & 7) * 128;

    const int lr = l >> 3, lc = l & 7;
    const int gcol = (lc ^ lr) << 3;
    const short* bgp = wbf + (size_t)(n0g + wv * 32 + lr) * D_ + gcol;
    short* aldsb = As + wv * 16 * 64;
    short* bldsb = Bs + wv * 32 * 64;

    size_t abase[2];
#pragma unroll
    for (int c = 0; c < 2; ++c) {
        int m = m0 + wv * 16 + c * 8 + lr;
        int bb2 = m >> 11, t = m & (T_ - 1);
        abase[c] = ((size_t)(bb2 * H_) * T_ + t) * HD_ + gcol;
    }

    floatx4 acc[2][4] = {};

    for (int k0 = 0; k0 < D_; k0 += 64) {
        const size_t hoff = (size_t)(k0 >> 6) * T_ * HD_;
        __syncthreads();
#pragma unroll
        for (int c = 0; c < 2; ++c)
            GLDS16(Abf + abase[c] + hoff, aldsb + c * 512);
#pragma unroll
        for (int c = 0; c < 4; ++c)
            GLDS16(bgp + (size_t)(c * 8) * D_ + k0, bldsb + c * 512);
        __syncthreads();

#pragma unroll
        for (int kk = 0; kk < 2; ++kk) {
            const int csw = (kk << 2) + quad;
            const int sw = (csw ^ (ln & 7)) << 3;
            shortx8 af[2], bf[4];
#pragma unroll
            for (int i = 0; i < 2; ++i)
                af[i] = *reinterpret_cast<const shortx8*>(&As[((wm * 32 + i * 16 + ln) << 6) + sw]);
#pragma unroll
            for (int j = 0; j < 4; ++j)
                bf[j] = *reinterpret_cast<const shortx8*>(&Bs[((wn * 64 + j * 16 + ln) << 6) + sw]);
#pragma unroll
            for (int i = 0; i < 2; ++i)
#pragma unroll
                for (int j = 0; j < 4; ++j)
                    acc[i][j] = __builtin_amdgcn_mfma_f32_16x16x32_bf16(af[i], bf[j], acc[i][j], 0, 0, 0);
        }
    }

#pragma unroll
    for (int i = 0; i < 2; ++i)
#pragma unroll
        for (int r = 0; r < 4; ++r) {
            int m = m0 + wm * 32 + i * 16 + rowb + r;
#pragma unroll
            for (int j = 0; j < 4; ++j)
                out[(size_t)m * D_ + n0g + wn * 64 + j * 16 + ln] = acc[i][j][r];
        }
}

// ---------------- flash attention, 32x32 MFMA, in-register softmax ----------
// R3 grid/mapping/reg-staging + single-barrier double-buffered inner loop
// (proven R11). 1024 blocks (128 thr, 4/CU); blocks >= 1024 cvt w_out.
__global__ __launch_bounds__(128, 2) void attn(const short* __restrict__ qws,
                                               const short* __restrict__ kv,
                                               short* ao,
                                               const float* __restrict__ wout,
                                               short* __restrict__ wobf) {
    if (blockIdx.x >= 1024) {
        int i = (blockIdx.x - 1024) * 128 + threadIdx.x;   // 1024 blocks -> 131072 groups
        const floatx4* p = reinterpret_cast<const floatx4*>(wout) + (size_t)i * 2;
        *(reinterpret_cast<shortx8*>(wobf) + i) = cvt8(p[0], p[1]);
        return;
    }

    __shared__ __align__(16) short Ks[2][64][72];
    __shared__ __align__(16) short Vt[2][64][72];

    const int tid = threadIdx.x;
    const int wv = tid >> 6;          // 0,1
    const int l  = tid & 63;
    const int ql = l & 31;
    const int hi = l >> 5;

    // balanced mapping: rounds t=0..3 per CU get qblk {31-r, r, 23-r, 8+r}
    const int id  = blockIdx.x;
    const int xcd = id & 7;
    const int u2  = (id >> 3) & 3;
    const int rr  = (id >> 5) & 7;
    const int tt  = id >> 8;
    const int bh  = xcd * 4 + u2;     // 4 heads per XCD
    const int qblk = (tt == 0) ? 31 - rr : (tt == 1) ? rr : (tt == 2) ? 23 - rr : 8 + rr;
    const int h = bh & 15, b = bh >> 4;

    const float slope2 = 1.4426950408889634f * exp2f(-(float)(h + 1) * 0.0625f);
    const size_t koff = (size_t)(b * H_ + h) * T_ * HD_;
    const int q0w = qblk * 64 + wv * 32;
    const int e = qblk + 1;           // kv-tile extent

    // Q fragments (B-operand): qf[ds] = Q[q0w+ql][ds*16 + hi*8 + 0..7]
    shortx8 qf[4];
#pragma unroll
    for (int ds = 0; ds < 4; ++ds)
        qf[ds] = *reinterpret_cast<const shortx8*>(&qws[koff + (size_t)(q0w + ql) * HD_ + ds * 16 + hi * 8]);

    // per-lane softmax bias base: exponent = s + rb[g] + slope2*(kb*64 + nc*32)
    const float cbase = slope2 * (float)(4 * hi - (q0w + ql)) - SMAX2;
    float rb[16];
#pragma unroll
    for (int g = 0; g < 16; ++g)
        rb[g] = cbase + slope2 * (float)((g & 3) + 8 * (g >> 2));
    const float s32 = slope2 * 32.0f;

    // staging: thread -> 64B contiguous of K row sr and V row sr
    const int sr = tid >> 1;
    const int sc = (tid & 1) << 5;
    const short* kbase = kv + koff;
    const short* vbase = kv + FULLH + koff;
    shortx8 kR[4], vR[4];
    auto FETCH = [&](int kb) {
        const short* kp = kbase + (((size_t)(kb * 64 + sr)) << 6) + sc;
        const short* vp = vbase + (size_t)sr * T_ + kb * 64 + sc;
#pragma unroll
        for (int s = 0; s < 4; ++s) {
            kR[s] = *reinterpret_cast<const shortx8*>(kp + 8 * s);
            vR[s] = *reinterpret_cast<const shortx8*>(vp + 8 * s);
        }
    };
    auto STAGE = [&](int bi) {
#pragma unroll
        for (int s = 0; s < 4; ++s) {
            *reinterpret_cast<shortx8*>(&Ks[bi][sr][sc + 8 * s]) = kR[s];
            *reinterpret_cast<shortx8*>(&Vt[bi][sr][sc + 8 * s]) = vR[s];
        }
    };

    floatx16 o0 = {}, o1 = {}, ls = {};
    const shortx8 ones = {16256, 16256, 16256, 16256, 16256, 16256, 16256, 16256};
    const int qlh = ql - 4 * hi;

    // prologue: fill buffer 0, prefetch tile 1 into regs
    FETCH(0);
    STAGE(0);
    if (e > 1) FETCH(1);
    __syncthreads();

    for (int kb = 0; kb < e; ++kb) {
        const int cur = kb & 1;
        if (kb + 1 < e) {
            STAGE(cur ^ 1);                    // regs of FETCH(kb+1)
            if (kb + 2 < e) FETCH(kb + 2);     // issued before COMP -> covered
        }

        const bool diag = (kb == qblk);
        const float tb = slope2 * (float)(kb * 64);

#pragma unroll
        for (int nc = 0; nc < 2; ++nc) {
            const bool act = !diag || (nc == 0) || (wv == 1);
            if (!act) continue;                     // wave-uniform
            const bool part = diag && (nc == wv);   // partial causal mask

            floatx16 sacc = {};
#pragma unroll
            for (int ds = 0; ds < 4; ++ds) {
                shortx8 kf = *reinterpret_cast<const shortx8*>(&Ks[cur][nc * 32 + ql][ds * 16 + hi * 8]);
                sacc = __builtin_amdgcn_mfma_f32_32x32x16_bf16(kf, qf[ds], sacc, 0, 0, 0);
            }

            const float tnc = tb + (nc ? s32 : 0.0f);
            float p[16];
#pragma unroll
            for (int g = 0; g < 16; ++g) {
                float ev = ex2(sacc[g] + (rb[g] + tnc));
                if (part) {
                    const int kc2 = (g & 3) + 8 * (g >> 2);
                    ev = (kc2 <= qlh) ? ev : 0.0f;
                }
                p[g] = ev;
            }

            unsigned cv[4][2];
#pragma unroll
            for (int g = 0; g < 4; ++g) {
                cv[g][0] = pk2(p[4 * g + 0], p[4 * g + 1]);
                cv[g][1] = pk2(p[4 * g + 2], p[4 * g + 3]);
            }

            __builtin_amdgcn_s_setprio(1);
#pragma unroll
            for (int kh = 0; kh < 2; ++kh) {
                unsigned w0 = cv[2 * kh][0], w2 = cv[2 * kh + 1][0];
                unsigned w1 = cv[2 * kh][1], w3 = cv[2 * kh + 1][1];
                asm volatile("v_permlane32_swap_b32 %0, %1" : "+v"(w0), "+v"(w2));
                asm volatile("v_permlane32_swap_b32 %0, %1" : "+v"(w1), "+v"(w3));
                uintx4 uu = {w0, w1, w2, w3};
                shortx8 apv = __builtin_bit_cast(shortx8, uu);
                const int ks = nc * 2 + kh;
                ls = __builtin_amdgcn_mfma_f32_32x32x16_bf16(apv, ones, ls, 0, 0, 0);
                shortx8 vf0 = *reinterpret_cast<const shortx8*>(&Vt[cur][ql][ks * 16 + hi * 8]);
                o0 = __builtin_amdgcn_mfma_f32_32x32x16_bf16(apv, vf0, o0, 0, 0, 0);
                shortx8 vf1 = *reinterpret_cast<const shortx8*>(&Vt[cur][32 + ql][ks * 16 + hi * 8]);
                o1 = __builtin_amdgcn_mfma_f32_32x32x16_bf16(apv, vf1, o1, 0, 0, 0);
            }
            __builtin_amdgcn_s_setprio(0);
        }
        __syncthreads();   // one barrier per tile
    }

    // epilogue: O and lsum share layout -> lane-local normalize
#pragma unroll
    for (int g = 0; g < 16; ++g) {
        const int qrow = (g & 3) + 8 * (g >> 2) + 4 * hi;
        const float inv = 1.0f / ls[g];
        const size_t ob = koff + (size_t)(q0w + qrow) * HD_ + ql;
        ao[ob]      = f2bf(o0[g] * inv);
        ao[ob + 32] = f2bf(o1[g] * inv);
    }
}

// ================= FALLBACK PATH (R8, fp32 inputs) =================
__global__ __launch_bounds__(256) void qkv_slow(const float* __restrict__ x,
                                                const float* __restrict__ wqkv,
                                                short* __restrict__ qout,
                                                short* __restrict__ kv) {
    __shared__ __align__(16) short As[64][72];
    __shared__ __align__(16) short Bs[64][72];
    const int tid = threadIdx.x;
    const int wv = tid >> 6, l = tid & 63, ln = l & 15, quad = l >> 4, qd = quad << 3;
    const int m0 = blockIdx.y * 64;
    const int sel = blockIdx.x >> 4, h = blockIdx.x & 15;
    const int nrow = sel * D_ + h * HD_;
    const int sr0 = tid >> 3, sc0 = (tid & 7) << 3, sr1 = sr0 + 32;
    floatx4 fa[4], fb[4];
    auto FETCH = [&](int k0) {
        const float* ap = &x[(size_t)(m0 + sr0) * D_ + k0 + sc0];
        fa[0] = *reinterpret_cast<const floatx4*>(ap);
        fa[1] = *reinterpret_cast<const floatx4*>(ap + 4);
        ap += (size_t)32 * D_;
        fa[2] = *reinterpret_cast<const floatx4*>(ap);
        fa[3] = *reinterpret_cast<const floatx4*>(ap + 4);
        const float* bp = &wqkv[(size_t)(nrow + sr0) * D_ + k0 + sc0];
        fb[0] = *reinterpret_cast<const floatx4*>(bp);
        fb[1] = *reinterpret_cast<const floatx4*>(bp + 4);
        bp += (size_t)32 * D_;
        fb[2] = *reinterpret_cast<const floatx4*>(bp);
        fb[3] = *reinterpret_cast<const floatx4*>(bp + 4);
    };
    floatx4 acc[4] = {};
    FETCH(0);
    for (int k0 = 0; k0 < D_; k0 += 64) {
        __syncthreads();
        *reinterpret_cast<shortx8*>(&As[sr0][sc0]) = cvt8(fa[0], fa[1]);
        *reinterpret_cast<shortx8*>(&As[sr1][sc0]) = cvt8(fa[2], fa[3]);
        *reinterpret_cast<shortx8*>(&Bs[sr0][sc0]) = cvt8(fb[0], fb[1]);
        *reinterpret_cast<shortx8*>(&Bs[sr1][sc0]) = cvt8(fb[2], fb[3]);
        __syncthreads();
        if (k0 + 64 < D_) FETCH(k0 + 64);
        const int mr = (wv << 4) + ln;
#pragma unroll
        for (int kk = 0; kk < 2; ++kk) {
            shortx8 a = *reinterpret_cast<const shortx8*>(&As[mr][kk * 32 + qd]);
#pragma unroll
            for (int nc = 0; nc < 4; ++nc) {
                shortx8 bq = *reinterpret_cast<const shortx8*>(&Bs[nc * 16 + ln][kk * 32 + qd]);
                acc[nc] = __builtin_amdgcn_mfma_f32_16x16x32_bf16(a, bq, acc[nc], 0, 0, 0);
            }
        }
    }
    const int bb = m0 >> 11, t0 = m0 & (T_ - 1);
    if (sel < 2) {
        short* dst = (sel == 0) ? qout : kv;
        const float sc = (sel == 0) ? QSCALE : 1.0f;   // Q carries log2e
#pragma unroll
        for (int r = 0; r < 4; ++r) {
            int t = t0 + (wv << 4) + (quad << 2) + r;
#pragma unroll
            for (int nc = 0; nc < 4; ++nc)
                dst[((size_t)(bb * H_ + h) * T_ + t) * HD_ + nc * 16 + ln] = f2bf(acc[nc][r] * sc);
        }
    } else {
        __syncthreads();
#pragma unroll
        for (int r = 0; r < 4; ++r)
#pragma unroll
            for (int nc = 0; nc < 4; ++nc)
                As[nc * 16 + ln][(wv << 4) + (quad << 2) + r] = f2bf(acc[nc][r]);
        __syncthreads();
        const int d = tid >> 2, tseg = (tid & 3) << 4;
        short* vdst = kv + FULLH + ((size_t)(bb * H_ + h) * HD_ + d) * T_ + t0 + tseg;
        *reinterpret_cast<shortx8*>(vdst)     = *reinterpret_cast<const shortx8*>(&As[d][tseg]);
        *reinterpret_cast<shortx8*>(vdst + 8) = *reinterpret_cast<const shortx8*>(&As[d][tseg + 8]);
    }
}

__global__ __launch_bounds__(256) void out_slow(const short* __restrict__ A,
                                                const float* __restrict__ W,
                                                float* __restrict__ out) {
    __shared__ __align__(16) short As[64][72];
    __shared__ __align__(16) short Bs[64][72];
    const int tid = threadIdx.x;
    const int wv = tid >> 6, l = tid & 63, ln = l & 15, quad = l >> 4, qd = quad << 3;
    const int m0 = blockIdx.y * 64, n0 = blockIdx.x * 64;
    const int sr0 = tid >> 3, sc0 = (tid & 7) << 3, sr1 = sr0 + 32;
    shortx8 sa0, sa1;
    floatx4 fb[4];
    auto FETCH = [&](int k0) {
        const int h = k0 >> 6;
        int m = m0 + sr0;
        int bb = m >> 11, t = m & (T_ - 1);
        sa0 = *reinterpret_cast<const shortx8*>(A + ((size_t)(bb * H_ + h) * T_ + t) * HD_ + sc0);
        m = m0 + sr1; bb = m >> 11; t = m & (T_ - 1);
        sa1 = *reinterpret_cast<const shortx8*>(A + ((size_t)(bb * H_ + h) * T_ + t) * HD_ + sc0);
        const float* bp = &W[(size_t)(n0 + sr0) * D_ + k0 + sc0];
        fb[0] = *reinterpret_cast<const floatx4*>(bp);
        fb[1] = *reinterpret_cast<const floatx4*>(bp + 4);
        bp += (size_t)32 * D_;
        fb[2] = *reinterpret_cast<const floatx4*>(bp);
        fb[3] = *reinterpret_cast<const floatx4*>(bp + 4);
    };
    floatx4 acc[4] = {};
    FETCH(0);
    for (int k0 = 0; k0 < D_; k0 += 64) {
        __syncthreads();
        *reinterpret_cast<shortx8*>(&As[sr0][sc0]) = sa0;
        *reinterpret_cast<shortx8*>(&As[sr1][sc0]) = sa1;
        *reinterpret_cast<shortx8*>(&Bs[sr0][sc0]) = cvt8(fb[0], fb[1]);
        *reinterpret_cast<shortx8*>(&Bs[sr1][sc0]) = cvt8(fb[2], fb[3]);
        __syncthreads();
        if (k0 + 64 < D_) FETCH(k0 + 64);
        const int mr = (wv << 4) + ln;
#pragma unroll
        for (int kk = 0; kk < 2; ++kk) {
            shortx8 a = *reinterpret_cast<const shortx8*>(&As[mr][kk * 32 + qd]);
#pragma unroll
            for (int nc = 0; nc < 4; ++nc) {
                shortx8 bq = *reinterpret_cast<const shortx8*>(&Bs[nc * 16 + ln][kk * 32 + qd]);
                acc[nc] = __builtin_amdgcn_mfma_f32_16x16x32_bf16(a, bq, acc[nc], 0, 0, 0);
            }
        }
    }
#pragma unroll
    for (int r = 0; r < 4; ++r) {
        int m = m0 + (wv << 4) + (quad << 2) + r;
#pragma unroll
        for (int nc = 0; nc < 4; ++nc)
            out[(size_t)m * D_ + n0 + nc * 16 + ln] = acc[nc][r];
    }
}

extern "C" void kernel_launch(void* const* d_in, const int* in_sizes, int n_in,
                              void* d_out, int out_size, void* d_ws, size_t ws_size,
                              hipStream_t stream) {
    const float* x    = (const float*)d_in[0];
    const float* wqkv = (const float*)d_in[1];
    const float* wout = (const float*)d_in[2];

    short* kvbuf = (short*)d_out;    // K head-major + V dim-major bf16: 16MB
    float* out   = (float*)d_out;

    if (ws_size >= 23068672ULL) {    // 22 MiB fast path
        short* qws  = (short*)d_ws;            // 4M shorts (Q, then attn out in place)
        short* wobf = qws + 4 * 1024 * 1024;   // 1M shorts (bf16 w_out)

        qkv_fast<<<dim3(768), 256, 0, stream>>>(x, wqkv, qws, kvbuf);
        attn<<<dim3(2048), 128, 0, stream>>>(qws, kvbuf, qws, wout, wobf);
        out_fast<<<dim3(512), 256, 0, stream>>>(qws, wobf, out);
    } else {                          // proven R8 fallback
        short* qws = (short*)d_ws;
        qkv_slow<<<dim3(48, 64), 256, 0, stream>>>(x, wqkv, qws, kvbuf);
        attn<<<dim3(1024), 128, 0, stream>>>(qws, kvbuf, qws, nullptr, nullptr);
        out_slow<<<dim3(16, 64), 256, 0, stream>>>(qws, wout, out);
    }
}

// Round 14
// 178.570 us; speedup vs baseline: 1.3301x; 1.3301x over previous
//
#include <hip/hip_runtime.h>
#include <hip/hip_bf16.h>

typedef __attribute__((ext_vector_type(8))) short shortx8;
typedef __attribute__((ext_vector_type(4))) float floatx4;
typedef __attribute__((ext_vector_type(16))) float floatx16;
typedef __attribute__((ext_vector_type(4))) unsigned uintx4;
typedef __attribute__((ext_vector_type(2))) unsigned uintx2;

#define B_ 2
#define T_ 2048
#define D_ 1024
#define H_ 16
#define HD_ 64
#define SCALE 0.125f
// log2(e)-folded constants: Q is pre-scaled by SCALE*log2e, softmax uses exp2.
#define QSCALE 0.18033688011112042f   /* 0.125 * log2(e) */
#define SMAX2 23.083120654223414f     /* 16 * log2(e) */
#define FULLH ((size_t)B_ * H_ * T_ * HD_)

// async global->LDS, 16B per lane; LDS dest = wave-uniform base + lane*16
#define GLDS16(g, l) __builtin_amdgcn_global_load_lds( \
    (__attribute__((address_space(1))) void*)(g), \
    (__attribute__((address_space(3))) void*)(l), 16, 0, 0)

__device__ __forceinline__ short f2bf(float f) {
    union { float f; unsigned u; } v; v.f = f;
    unsigned r = v.u + 0x7FFFu + ((v.u >> 16) & 1u);
    return (short)(r >> 16);
}

__device__ __forceinline__ unsigned pk2(float x, float y) {
    union { __hip_bfloat162 h; unsigned u; } t;
    t.h = __float22bfloat162_rn(make_float2(x, y));
    return t.u;
}

__device__ __forceinline__ shortx8 cvt8(floatx4 a, floatx4 b) {
    uintx4 r = { pk2(a[0], a[1]), pk2(a[2], a[3]), pk2(b[0], b[1]), pk2(b[2], b[3]) };
    return __builtin_bit_cast(shortx8, r);
}

__device__ __forceinline__ float ex2(float x) {
#if __has_builtin(__builtin_amdgcn_exp2f)
    return __builtin_amdgcn_exp2f(x);
#else
    return exp2f(x);
#endif
}

// ---------------- fp32 -> bf16 bulk convert (x + w_qkv merged, one launch) ----
// Compression pre-pass: downstream panel re-reads are half-width and L2/L3-
// absorbed (R13 lesson: fusing this into the GEMM doubles HBM traffic).
__global__ __launch_bounds__(256) void cvt_xw(const float* __restrict__ x,
                                              const float* __restrict__ wqkv,
                                              short* __restrict__ xbf,
                                              short* __restrict__ wbf) {
    int i = blockIdx.x * 256 + threadIdx.x;
    const float* src; short* dst; int o;
    if (i < 524288) { src = x; dst = xbf; o = i; }
    else            { src = wqkv; dst = wbf; o = i - 524288; }
    const floatx4* p = reinterpret_cast<const floatx4*>(src) + (size_t)o * 2;
    *(reinterpret_cast<shortx8*>(dst) + o) = cvt8(p[0], p[1]);
}

// ================= FAST PATH (bf16 inputs, m97-style) =================
// Q/K/V projection. 1D grid 768, XCD-grouped + A-chunked (R12's mapping,
// FETCH-proven 68.7->47.2 MB): xcd=id&7 owns bx in {3*xcd..3*xcd+2};
// per XCD iterate {chunk of 8 by} x {3 bx} (byi fastest) so the 2MB
// A-chunk + 768KB B-panels stay L2-resident. Single-buffer GLDS16 (R11).
__global__ __launch_bounds__(256) void qkv_fast(const short* __restrict__ xbf,
                                                const short* __restrict__ wbf,
                                                short* __restrict__ qout,
                                                short* __restrict__ kv) {
    __shared__ __align__(16) short As[128 * 64];
    __shared__ __align__(16) short Bs[128 * 64];

    const int tid = threadIdx.x;
    const int wv = tid >> 6;
    const int l  = tid & 63;
    const int ln = l & 15;
    const int quad = l >> 4;
    const int rowb = quad << 2;
    const int wm = wv >> 1, wn = wv & 1;

    const int id  = blockIdx.x;
    const int xcd = id & 7;
    const int tt  = id >> 3;               // 0..95
    const int byi = tt & 7;
    const int u   = tt >> 3;               // 0..11
    const int bxl = u % 3;
    const int chunk = u / 3;               // 0..3
    const int bx = xcd * 3 + bxl;          // 0..23
    const int by = chunk * 8 + byi;        // 0..31
    const int m0 = by * 128;
    const int n0g = bx * 128;

    const int lr = l >> 3, lc = l & 7;
    const int gcol = (lc ^ lr) << 3;                 // swizzled source chunk
    const short* agp = xbf + (size_t)(m0 + wv * 32 + lr) * D_ + gcol;
    const short* bgp = wbf + (size_t)(n0g + wv * 32 + lr) * D_ + gcol;
    short* aldsb = As + wv * 32 * 64;
    short* bldsb = Bs + wv * 32 * 64;

    floatx4 acc[4][4] = {};

    for (int k0 = 0; k0 < D_; k0 += 64) {
        __syncthreads();
#pragma unroll
        for (int c = 0; c < 4; ++c) {
            GLDS16(agp + (size_t)(c * 8) * D_ + k0, aldsb + c * 512);
            GLDS16(bgp + (size_t)(c * 8) * D_ + k0, bldsb + c * 512);
        }
        __syncthreads();

#pragma unroll
        for (int kk = 0; kk < 2; ++kk) {
            const int csw = (kk << 2) + quad;
            const int sw = (csw ^ (ln & 7)) << 3;
            shortx8 af[4], bf[4];
#pragma unroll
            for (int i = 0; i < 4; ++i)
                af[i] = *reinterpret_cast<const shortx8*>(&As[((wm * 64 + i * 16 + ln) << 6) + sw]);
#pragma unroll
            for (int j = 0; j < 4; ++j)
                bf[j] = *reinterpret_cast<const shortx8*>(&Bs[((wn * 64 + j * 16 + ln) << 6) + sw]);
#pragma unroll
            for (int i = 0; i < 4; ++i)
#pragma unroll
                for (int j = 0; j < 4; ++j)
                    acc[i][j] = __builtin_amdgcn_mfma_f32_16x16x32_bf16(af[i], bf[j], acc[i][j], 0, 0, 0);
        }
    }

    const int sel = n0g >> 10;
    const int bb = m0 >> 11;
    const int t0w = (m0 + wm * 64) & (T_ - 1);
    const int h = ((n0g + wn * 64) >> 6) & 15;

    if (sel < 2) {
        short* dst = (sel == 0) ? qout : kv;
        const float sc = (sel == 0) ? QSCALE : 1.0f;   // Q carries log2e
        const size_t hb = (size_t)(bb * H_ + h) * T_;
#pragma unroll
        for (int i = 0; i < 4; ++i)
#pragma unroll
            for (int r = 0; r < 4; ++r) {
                int t = t0w + i * 16 + rowb + r;
#pragma unroll
                for (int j = 0; j < 4; ++j)
                    dst[(hb + t) * HD_ + j * 16 + ln] = f2bf(acc[i][j][r] * sc);
            }
    } else {
        // V -> dim-major [b][h][d][t], 2-pass per-wave LDS transpose (As/Bs dead)
        __syncthreads();
        short* tb = (wv < 2) ? (As + wv * 4096) : (Bs + (wv - 2) * 4096);  // 32x72 region
        short* vhead = kv + FULLH + (size_t)(bb * H_ + h) * HD_ * T_;
        const int dl = l & 31, th = (l >> 5) << 5;
#pragma unroll
        for (int p = 0; p < 2; ++p) {
#pragma unroll
            for (int i = 0; i < 4; ++i)
#pragma unroll
                for (int jj = 0; jj < 2; ++jj) {
                    int j = 2 * p + jj;
#pragma unroll
                    for (int r = 0; r < 4; ++r)
                        tb[(jj * 16 + ln) * 72 + i * 16 + rowb + r] = f2bf(acc[i][j][r]);
                }
            short* vd = vhead + (size_t)(p * 32 + dl) * T_ + t0w + th;
#pragma unroll
            for (int seg = 0; seg < 4; ++seg)
                *reinterpret_cast<shortx8*>(vd + seg * 8) =
                    *reinterpret_cast<const shortx8*>(&tb[dl * 72 + th + seg * 8]);
        }
    }
}

// Final projection, BM=64 x BN=128. 1D grid 512: bx = id&7 (one B-panel per
// XCD, L2-resident), by = id>>3 -> 2 blocks/CU.
__global__ __launch_bounds__(256) void out_fast(const short* __restrict__ Abf,
                                                const short* __restrict__ wbf,
                                                float* __restrict__ out) {
    __shared__ __align__(16) short As[64 * 64];    // 8 KB
    __shared__ __align__(16) short Bs[128 * 64];   // 16 KB

    const int tid = threadIdx.x;
    const int wv = tid >> 6;
    const int l  = tid & 63;
    const int ln = l & 15;
    const int quad = l >> 4;
    const int rowb = quad << 2;
    const int wm = wv >> 1, wn = wv & 1;

    const int id = blockIdx.x;
    const int m0 = (id >> 3) * 64;
    const int n0g = (id & 7) * 128;

    const int lr = l >> 3, lc = l & 7;
    const int gcol = (lc ^ lr) << 3;
    const short* bgp = wbf + (size_t)(n0g + wv * 32 + lr) * D_ + gcol;
    short* aldsb = As + wv * 16 * 64;
    short* bldsb = Bs + wv * 32 * 64;

    size_t abase[2];
#pragma unroll
    for (int c = 0; c < 2; ++c) {
        int m = m0 + wv * 16 + c * 8 + lr;
        int bb2 = m >> 11, t = m & (T_ - 1);
        abase[c] = ((size_t)(bb2 * H_) * T_ + t) * HD_ + gcol;
    }

    floatx4 acc[2][4] = {};

    for (int k0 = 0; k0 < D_; k0 += 64) {
        const size_t hoff = (size_t)(k0 >> 6) * T_ * HD_;
        __syncthreads();
#pragma unroll
        for (int c = 0; c < 2; ++c)
            GLDS16(Abf + abase[c] + hoff, aldsb + c * 512);
#pragma unroll
        for (int c = 0; c < 4; ++c)
            GLDS16(bgp + (size_t)(c * 8) * D_ + k0, bldsb + c * 512);
        __syncthreads();

#pragma unroll
        for (int kk = 0; kk < 2; ++kk) {
            const int csw = (kk << 2) + quad;
            const int sw = (csw ^ (ln & 7)) << 3;
            shortx8 af[2], bf[4];
#pragma unroll
            for (int i = 0; i < 2; ++i)
                af[i] = *reinterpret_cast<const shortx8*>(&As[((wm * 32 + i * 16 + ln) << 6) + sw]);
#pragma unroll
            for (int j = 0; j < 4; ++j)
                bf[j] = *reinterpret_cast<const shortx8*>(&Bs[((wn * 64 + j * 16 + ln) << 6) + sw]);
#pragma unroll
            for (int i = 0; i < 2; ++i)
#pragma unroll
                for (int j = 0; j < 4; ++j)
                    acc[i][j] = __builtin_amdgcn_mfma_f32_16x16x32_bf16(af[i], bf[j], acc[i][j], 0, 0, 0);
        }
    }

#pragma unroll
    for (int i = 0; i < 2; ++i)
#pragma unroll
        for (int r = 0; r < 4; ++r) {
            int m = m0 + wm * 32 + i * 16 + rowb + r;
#pragma unroll
            for (int j = 0; j < 4; ++j)
                out[(size_t)m * D_ + n0g + wn * 64 + j * 16 + ln] = acc[i][j][r];
        }
}

// ---------------- flash attention, 32x32 MFMA, in-register softmax ----------
// R3 grid/mapping/reg-staging + single-barrier double-buffered inner loop
// (proven R11). 1024 blocks (128 thr, 4/CU); blocks >= 1024 cvt w_out.
__global__ __launch_bounds__(128, 2) void attn(const short* __restrict__ qws,
                                               const short* __restrict__ kv,
                                               short* ao,
                                               const float* __restrict__ wout,
                                               short* __restrict__ wobf) {
    if (blockIdx.x >= 1024) {
        int i = (blockIdx.x - 1024) * 128 + threadIdx.x;   // 1024 blocks -> 131072 groups
        const floatx4* p = reinterpret_cast<const floatx4*>(wout) + (size_t)i * 2;
        *(reinterpret_cast<shortx8*>(wobf) + i) = cvt8(p[0], p[1]);
        return;
    }

    __shared__ __align__(16) short Ks[2][64][72];
    __shared__ __align__(16) short Vt[2][64][72];

    const int tid = threadIdx.x;
    const int wv = tid >> 6;          // 0,1
    const int l  = tid & 63;
    const int ql = l & 31;
    const int hi = l >> 5;

    // balanced mapping: rounds t=0..3 per CU get qblk {31-r, r, 23-r, 8+r}
    const int id  = blockIdx.x;
    const int xcd = id & 7;
    const int u2  = (id >> 3) & 3;
    const int rr  = (id >> 5) & 7;
    const int tt  = id >> 8;
    const int bh  = xcd * 4 + u2;     // 4 heads per XCD
    const int qblk = (tt == 0) ? 31 - rr : (tt == 1) ? rr : (tt == 2) ? 23 - rr : 8 + rr;
    const int h = bh & 15, b = bh >> 4;

    const float slope2 = 1.4426950408889634f * exp2f(-(float)(h + 1) * 0.0625f);
    const size_t koff = (size_t)(b * H_ + h) * T_ * HD_;
    const int q0w = qblk * 64 + wv * 32;
    const int e = qblk + 1;           // kv-tile extent

    // Q fragments (B-operand): qf[ds] = Q[q0w+ql][ds*16 + hi*8 + 0..7]
    shortx8 qf[4];
#pragma unroll
    for (int ds = 0; ds < 4; ++ds)
        qf[ds] = *reinterpret_cast<const shortx8*>(&qws[koff + (size_t)(q0w + ql) * HD_ + ds * 16 + hi * 8]);

    // per-lane softmax bias base: exponent = s + rb[g] + slope2*(kb*64 + nc*32)
    const float cbase = slope2 * (float)(4 * hi - (q0w + ql)) - SMAX2;
    float rb[16];
#pragma unroll
    for (int g = 0; g < 16; ++g)
        rb[g] = cbase + slope2 * (float)((g & 3) + 8 * (g >> 2));
    const float s32 = slope2 * 32.0f;

    // staging: thread -> 64B contiguous of K row sr and V row sr
    const int sr = tid >> 1;
    const int sc = (tid & 1) << 5;
    const short* kbase = kv + koff;
    const short* vbase = kv + FULLH + koff;
    shortx8 kR[4], vR[4];
    auto FETCH = [&](int kb) {
        const short* kp = kbase + (((size_t)(kb * 64 + sr)) << 6) + sc;
        const short* vp = vbase + (size_t)sr * T_ + kb * 64 + sc;
#pragma unroll
        for (int s = 0; s < 4; ++s) {
            kR[s] = *reinterpret_cast<const shortx8*>(kp + 8 * s);
            vR[s] = *reinterpret_cast<const shortx8*>(vp + 8 * s);
        }
    };
    auto STAGE = [&](int bi) {
#pragma unroll
        for (int s = 0; s < 4; ++s) {
            *reinterpret_cast<shortx8*>(&Ks[bi][sr][sc + 8 * s]) = kR[s];
            *reinterpret_cast<shortx8*>(&Vt[bi][sr][sc + 8 * s]) = vR[s];
        }
    };

    floatx16 o0 = {}, o1 = {}, ls = {};
    const shortx8 ones = {16256, 16256, 16256, 16256, 16256, 16256, 16256, 16256};
    const int qlh = ql - 4 * hi;

    // prologue: fill buffer 0, prefetch tile 1 into regs
    FETCH(0);
    STAGE(0);
    if (e > 1) FETCH(1);
    __syncthreads();

    for (int kb = 0; kb < e; ++kb) {
        const int cur = kb & 1;
        if (kb + 1 < e) {
            STAGE(cur ^ 1);                    // regs of FETCH(kb+1)
            if (kb + 2 < e) FETCH(kb + 2);     // issued before COMP -> covered
        }

        const bool diag = (kb == qblk);
        const float tb = slope2 * (float)(kb * 64);

#pragma unroll
        for (int nc = 0; nc < 2; ++nc) {
            const bool act = !diag || (nc == 0) || (wv == 1);
            if (!act) continue;                     // wave-uniform
            const bool part = diag && (nc == wv);   // partial causal mask

            floatx16 sacc = {};
#pragma unroll
            for (int ds = 0; ds < 4; ++ds) {
                shortx8 kf = *reinterpret_cast<const shortx8*>(&Ks[cur][nc * 32 + ql][ds * 16 + hi * 8]);
                sacc = __builtin_amdgcn_mfma_f32_32x32x16_bf16(kf, qf[ds], sacc, 0, 0, 0);
            }

            const float tnc = tb + (nc ? s32 : 0.0f);
            float p[16];
#pragma unroll
            for (int g = 0; g < 16; ++g) {
                float ev = ex2(sacc[g] + (rb[g] + tnc));
                if (part) {
                    const int kc2 = (g & 3) + 8 * (g >> 2);
                    ev = (kc2 <= qlh) ? ev : 0.0f;
                }
                p[g] = ev;
            }

            unsigned cv[4][2];
#pragma unroll
            for (int g = 0; g < 4; ++g) {
                cv[g][0] = pk2(p[4 * g + 0], p[4 * g + 1]);
                cv[g][1] = pk2(p[4 * g + 2], p[4 * g + 3]);
            }

            __builtin_amdgcn_s_setprio(1);
#pragma unroll
            for (int kh = 0; kh < 2; ++kh) {
                unsigned w0 = cv[2 * kh][0], w2 = cv[2 * kh + 1][0];
                unsigned w1 = cv[2 * kh][1], w3 = cv[2 * kh + 1][1];
                asm volatile("v_permlane32_swap_b32 %0, %1" : "+v"(w0), "+v"(w2));
                asm volatile("v_permlane32_swap_b32 %0, %1" : "+v"(w1), "+v"(w3));
                uintx4 uu = {w0, w1, w2, w3};
                shortx8 apv = __builtin_bit_cast(shortx8, uu);
                const int ks = nc * 2 + kh;
                ls = __builtin_amdgcn_mfma_f32_32x32x16_bf16(apv, ones, ls, 0, 0, 0);
                shortx8 vf0 = *reinterpret_cast<const shortx8*>(&Vt[cur][ql][ks * 16 + hi * 8]);
                o0 = __builtin_amdgcn_mfma_f32_32x32x16_bf16(apv, vf0, o0, 0, 0, 0);
                shortx8 vf1 = *reinterpret_cast<const shortx8*>(&Vt[cur][32 + ql][ks * 16 + hi * 8]);
                o1 = __builtin_amdgcn_mfma_f32_32x32x16_bf16(apv, vf1, o1, 0, 0, 0);
            }
            __builtin_amdgcn_s_setprio(0);
        }
        __syncthreads();   // one barrier per tile
    }

    // epilogue: O and lsum share layout -> lane-local normalize
#pragma unroll
    for (int g = 0; g < 16; ++g) {
        const int qrow = (g & 3) + 8 * (g >> 2) + 4 * hi;
        const float inv = 1.0f / ls[g];
        const size_t ob = koff + (size_t)(q0w + qrow) * HD_ + ql;
        ao[ob]      = f2bf(o0[g] * inv);
        ao[ob + 32] = f2bf(o1[g] * inv);
    }
}

// ================= FALLBACK PATH (R8, fp32 inputs) =================
__global__ __launch_bounds__(256) void qkv_slow(const float* __restrict__ x,
                                                const float* __restrict__ wqkv,
                                                short* __restrict__ qout,
                                                short* __restrict__ kv) {
    __shared__ __align__(16) short As[64][72];
    __shared__ __align__(16) short Bs[64][72];
    const int tid = threadIdx.x;
    const int wv = tid >> 6, l = tid & 63, ln = l & 15, quad = l >> 4, qd = quad << 3;
    const int m0 = blockIdx.y * 64;
    const int sel = blockIdx.x >> 4, h = blockIdx.x & 15;
    const int nrow = sel * D_ + h * HD_;
    const int sr0 = tid >> 3, sc0 = (tid & 7) << 3, sr1 = sr0 + 32;
    floatx4 fa[4], fb[4];
    auto FETCH = [&](int k0) {
        const float* ap = &x[(size_t)(m0 + sr0) * D_ + k0 + sc0];
        fa[0] = *reinterpret_cast<const floatx4*>(ap);
        fa[1] = *reinterpret_cast<const floatx4*>(ap + 4);
        ap += (size_t)32 * D_;
        fa[2] = *reinterpret_cast<const floatx4*>(ap);
        fa[3] = *reinterpret_cast<const floatx4*>(ap + 4);
        const float* bp = &wqkv[(size_t)(nrow + sr0) * D_ + k0 + sc0];
        fb[0] = *reinterpret_cast<const floatx4*>(bp);
        fb[1] = *reinterpret_cast<const floatx4*>(bp + 4);
        bp += (size_t)32 * D_;
        fb[2] = *reinterpret_cast<const floatx4*>(bp);
        fb[3] = *reinterpret_cast<const floatx4*>(bp + 4);
    };
    floatx4 acc[4] = {};
    FETCH(0);
    for (int k0 = 0; k0 < D_; k0 += 64) {
        __syncthreads();
        *reinterpret_cast<shortx8*>(&As[sr0][sc0]) = cvt8(fa[0], fa[1]);
        *reinterpret_cast<shortx8*>(&As[sr1][sc0]) = cvt8(fa[2], fa[3]);
        *reinterpret_cast<shortx8*>(&Bs[sr0][sc0]) = cvt8(fb[0], fb[1]);
        *reinterpret_cast<shortx8*>(&Bs[sr1][sc0]) = cvt8(fb[2], fb[3]);
        __syncthreads();
        if (k0 + 64 < D_) FETCH(k0 + 64);
        const int mr = (wv << 4) + ln;
#pragma unroll
        for (int kk = 0; kk < 2; ++kk) {
            shortx8 a = *reinterpret_cast<const shortx8*>(&As[mr][kk * 32 + qd]);
#pragma unroll
            for (int nc = 0; nc < 4; ++nc) {
                shortx8 bq = *reinterpret_cast<const shortx8*>(&Bs[nc * 16 + ln][kk * 32 + qd]);
                acc[nc] = __builtin_amdgcn_mfma_f32_16x16x32_bf16(a, bq, acc[nc], 0, 0, 0);
            }
        }
    }
    const int bb = m0 >> 11, t0 = m0 & (T_ - 1);
    if (sel < 2) {
        short* dst = (sel == 0) ? qout : kv;
        const float sc = (sel == 0) ? QSCALE : 1.0f;   // Q carries log2e
#pragma unroll
        for (int r = 0; r < 4; ++r) {
            int t = t0 + (wv << 4) + (quad << 2) + r;
#pragma unroll
            for (int nc = 0; nc < 4; ++nc)
                dst[((size_t)(bb * H_ + h) * T_ + t) * HD_ + nc * 16 + ln] = f2bf(acc[nc][r] * sc);
        }
    } else {
        __syncthreads();
#pragma unroll
        for (int r = 0; r < 4; ++r)
#pragma unroll
            for (int nc = 0; nc < 4; ++nc)
                As[nc * 16 + ln][(wv << 4) + (quad << 2) + r] = f2bf(acc[nc][r]);
        __syncthreads();
        const int d = tid >> 2, tseg = (tid & 3) << 4;
        short* vdst = kv + FULLH + ((size_t)(bb * H_ + h) * HD_ + d) * T_ + t0 + tseg;
        *reinterpret_cast<shortx8*>(vdst)     = *reinterpret_cast<const shortx8*>(&As[d][tseg]);
        *reinterpret_cast<shortx8*>(vdst + 8) = *reinterpret_cast<const shortx8*>(&As[d][tseg + 8]);
    }
}

__global__ __launch_bounds__(256) void out_slow(const short* __restrict__ A,
                                                const float* __restrict__ W,
                                                float* __restrict__ out) {
    __shared__ __align__(16) short As[64][72];
    __shared__ __align__(16) short Bs[64][72];
    const int tid = threadIdx.x;
    const int wv = tid >> 6, l = tid & 63, ln = l & 15, quad = l >> 4, qd = quad << 3;
    const int m0 = blockIdx.y * 64, n0 = blockIdx.x * 64;
    const int sr0 = tid >> 3, sc0 = (tid & 7) << 3, sr1 = sr0 + 32;
    shortx8 sa0, sa1;
    floatx4 fb[4];
    auto FETCH = [&](int k0) {
        const int h = k0 >> 6;
        int m = m0 + sr0;
        int bb = m >> 11, t = m & (T_ - 1);
        sa0 = *reinterpret_cast<const shortx8*>(A + ((size_t)(bb * H_ + h) * T_ + t) * HD_ + sc0);
        m = m0 + sr1; bb = m >> 11; t = m & (T_ - 1);
        sa1 = *reinterpret_cast<const shortx8*>(A + ((size_t)(bb * H_ + h) * T_ + t) * HD_ + sc0);
        const float* bp = &W[(size_t)(n0 + sr0) * D_ + k0 + sc0];
        fb[0] = *reinterpret_cast<const floatx4*>(bp);
        fb[1] = *reinterpret_cast<const floatx4*>(bp + 4);
        bp += (size_t)32 * D_;
        fb[2] = *reinterpret_cast<const floatx4*>(bp);
        fb[3] = *reinterpret_cast<const floatx4*>(bp + 4);
    };
    floatx4 acc[4] = {};
    FETCH(0);
    for (int k0 = 0; k0 < D_; k0 += 64) {
        __syncthreads();
        *reinterpret_cast<shortx8*>(&As[sr0][sc0]) = sa0;
        *reinterpret_cast<shortx8*>(&As[sr1][sc0]) = sa1;
        *reinterpret_cast<shortx8*>(&Bs[sr0][sc0]) = cvt8(fb[0], fb[1]);
        *reinterpret_cast<shortx8*>(&Bs[sr1][sc0]) = cvt8(fb[2], fb[3]);
        __syncthreads();
        if (k0 + 64 < D_) FETCH(k0 + 64);
        const int mr = (wv << 4) + ln;
#pragma unroll
        for (int kk = 0; kk < 2; ++kk) {
            shortx8 a = *reinterpret_cast<const shortx8*>(&As[mr][kk * 32 + qd]);
#pragma unroll
            for (int nc = 0; nc < 4; ++nc) {
                shortx8 bq = *reinterpret_cast<const shortx8*>(&Bs[nc * 16 + ln][kk * 32 + qd]);
                acc[nc] = __builtin_amdgcn_mfma_f32_16x16x32_bf16(a, bq, acc[nc], 0, 0, 0);
            }
        }
    }
#pragma unroll
    for (int r = 0; r < 4; ++r) {
        int m = m0 + (wv << 4) + (quad << 2) + r;
#pragma unroll
        for (int nc = 0; nc < 4; ++nc)
            out[(size_t)m * D_ + n0 + nc * 16 + ln] = acc[nc][r];
    }
}

extern "C" void kernel_launch(void* const* d_in, const int* in_sizes, int n_in,
                              void* d_out, int out_size, void* d_ws, size_t ws_size,
                              hipStream_t stream) {
    const float* x    = (const float*)d_in[0];
    const float* wqkv = (const float*)d_in[1];
    const float* wout = (const float*)d_in[2];

    short* kvbuf = (short*)d_out;    // K head-major + V dim-major bf16: 16MB
    float* out   = (float*)d_out;

    if (ws_size >= 23068672ULL) {    // 22 MiB fast path
        short* xbf  = (short*)d_ws;            // 4M shorts
        short* wbf  = xbf + 4 * 1024 * 1024;   // 3M shorts
        short* qws  = xbf + 7 * 1024 * 1024;   // 4M shorts (Q, then attn out in place)
        short* wobf = xbf;                     // overlays dead xbf after qkv_fast

        cvt_xw<<<3584, 256, 0, stream>>>(x, wqkv, xbf, wbf);
        qkv_fast<<<dim3(768), 256, 0, stream>>>(xbf, wbf, qws, kvbuf);
        attn<<<dim3(2048), 128, 0, stream>>>(qws, kvbuf, qws, wout, wobf);
        out_fast<<<dim3(512), 256, 0, stream>>>(qws, wobf, out);
    } else {                          // proven R8 fallback
        short* qws = (short*)d_ws;
        qkv_slow<<<dim3(48, 64), 256, 0, stream>>>(x, wqkv, qws, kvbuf);
        attn<<<dim3(1024), 128, 0, stream>>>(qws, kvbuf, qws, nullptr, nullptr);
        out_slow<<<dim3(16, 64), 256, 0, stream>>>(qws, wout, out);
    }
}